// Round 7
// baseline (63.080 us; speedup 1.0000x reference)
//
#include <hip/hip_runtime.h>

#define S 512
#define B 128
#define H 1024

#define KG 16          // k-groups (two-stage calc_u)
#define KR 64          // k per group: KG*KR == H
#define BPG 8          // b per stage-1 block
#define BG (B / BPG)   // 16 b-groups

// ---------------------------------------------------------------------------
// calc_u stage 1: part[kg][b][h] = sum_{k in kg-group} hidden[b][k]*W[k][h].
// 256 blocks x 256 threads; thread owns 4 h (float4 W loads, 1KB/wave-instr
// coalesced); hidden loads wave-uniform -> scalar pipe. Deterministic.
// ---------------------------------------------------------------------------
__global__ __launch_bounds__(256) void calc_u_part(const float* __restrict__ hidden,
                                                   const float* __restrict__ W,
                                                   float* __restrict__ part) {
    const int t  = threadIdx.x;
    const int kg = blockIdx.x & (KG - 1);
    const int bg = blockIdx.x >> 4;
    const int b0 = bg * BPG;
    const int h4 = t * 4;
    const int k0 = kg * KR;

    float4 acc[BPG];
#pragma unroll
    for (int j = 0; j < BPG; ++j) acc[j] = make_float4(0.f, 0.f, 0.f, 0.f);

#pragma unroll 8
    for (int kk = 0; kk < KR; ++kk) {
        const int k = k0 + kk;
        const float4 w = *reinterpret_cast<const float4*>(W + (size_t)k * H + h4);
#pragma unroll
        for (int j = 0; j < BPG; ++j) {
            const float hb = hidden[(size_t)(b0 + j) * H + k];  // uniform
            acc[j].x = fmaf(hb, w.x, acc[j].x);
            acc[j].y = fmaf(hb, w.y, acc[j].y);
            acc[j].z = fmaf(hb, w.z, acc[j].z);
            acc[j].w = fmaf(hb, w.w, acc[j].w);
        }
    }
#pragma unroll
    for (int j = 0; j < BPG; ++j)
        *reinterpret_cast<float4*>(part + ((size_t)kg * B + (b0 + j)) * H + h4) = acc[j];
}

// Stage 2: u = sum_kg part (float4) + zero the per-b completion counters.
// Kernel-end implicit device-scope release publishes both u and cnt to all
// XCDs before calc_scores starts (stream order).
__global__ __launch_bounds__(256) void calc_u_reduce(const float* __restrict__ part,
                                                     float* __restrict__ u,
                                                     int* __restrict__ cnt) {
    const int idx4 = blockIdx.x * 256 + threadIdx.x;  // float4 index in [B*H/4)
    const float4* __restrict__ p4 = reinterpret_cast<const float4*>(part);
    float4 s = p4[idx4];
#pragma unroll
    for (int kg = 1; kg < KG; ++kg) {
        float4 v = p4[(size_t)kg * (B * H / 4) + idx4];
        s.x += v.x; s.y += v.y; s.z += v.z; s.w += v.w;
    }
    reinterpret_cast<float4*>(u)[idx4] = s;
    if (blockIdx.x == 0 && threadIdx.x < B) cnt[threadIdx.x] = 0;
}

// Fallback single-stage calc_u (tiny workspace only).
__global__ __launch_bounds__(256) void calc_u_fallback(const float* __restrict__ hidden,
                                                       const float* __restrict__ W,
                                                       float* __restrict__ u,
                                                       int* __restrict__ cnt) {
    const int h  = (blockIdx.x & 3) * 256 + threadIdx.x;
    const int bb = blockIdx.x >> 2;
    const float* __restrict__ h0p = hidden + (size_t)bb * H;
    const float* __restrict__ h1p = hidden + (size_t)(bb + 64) * H;
    float acc0 = 0.f, acc1 = 0.f;
#pragma unroll 16
    for (int k = 0; k < H; ++k) {
        float w = W[(size_t)k * H + h];
        acc0 = fmaf(h0p[k], w, acc0);
        acc1 = fmaf(h1p[k], w, acc1);
    }
    u[(size_t)bb * H + h] = acc0;
    u[(size_t)(bb + 64) * H + h] = acc1;
    if (blockIdx.x == 0 && threadIdx.x < B) cnt[threadIdx.x] = 0;
}

// ---------------------------------------------------------------------------
// Fused scores + softmax, scoped-atomics version (NOT the R2 threadfence
// design — per-wave __threadfence = L2 writeback = 13x regression).
// Wave w: b = w&127, sg = w>>7; s in [sg*8, sg*8+8). u[b] in 16 VGPRs.
// Plain float4 enc loads (nt measured -1.9us: L3 hits don't help; fabric-
// capped ~5.4 TB/s either way). Tail protocol, all L3-coherence-point ops:
//   1. lane0: 8 relaxed agent-scope score stores (no cache flush, direct)
//   2. s_waitcnt vmcnt(0)   -- our stores only, ~300cyc, occupancy-hidden
//   3. lane0: relaxed agent-scope fetch_add(cnt[b]) -> old
//   4. the wave seeing old==63 re-reads all 512 scores via agent-scope
//      loads (all other waves' stores already at coherence point) and
//      does the row softmax in-wave. Deterministic values; no spin locks.
// ---------------------------------------------------------------------------
__global__ __launch_bounds__(256) void calc_scores_fused(const float* __restrict__ enc,
                                                         const float* __restrict__ u,
                                                         float* __restrict__ scores,
                                                         int* __restrict__ cnt,
                                                         float* __restrict__ out) {
    const int wid  = threadIdx.x >> 6;
    const int lane = threadIdx.x & 63;
    const int w  = blockIdx.x * 4 + wid;   // 0..8191
    const int b  = w & (B - 1);
    const int sg = w >> 7;                 // 0..63
    const int s0 = sg * 8;

    const float4* __restrict__ u4 = reinterpret_cast<const float4*>(u + (size_t)b * H);
    const float4 uu0 = u4[lane];
    const float4 uu1 = u4[64 + lane];
    const float4 uu2 = u4[128 + lane];
    const float4 uu3 = u4[192 + lane];

    float acc[8];
#pragma unroll
    for (int j = 0; j < 8; ++j) {
        const float4* __restrict__ e4 =
            reinterpret_cast<const float4*>(enc + ((size_t)(s0 + j) * B + b) * H);
        const float4 e0 = e4[lane];
        const float4 e1 = e4[64 + lane];
        const float4 e2 = e4[128 + lane];
        const float4 e3 = e4[192 + lane];
        float a = e0.x * uu0.x + e0.y * uu0.y + e0.z * uu0.z + e0.w * uu0.w;
        a = fmaf(e1.x, uu1.x, a); a = fmaf(e1.y, uu1.y, a);
        a = fmaf(e1.z, uu1.z, a); a = fmaf(e1.w, uu1.w, a);
        a = fmaf(e2.x, uu2.x, a); a = fmaf(e2.y, uu2.y, a);
        a = fmaf(e2.z, uu2.z, a); a = fmaf(e2.w, uu2.w, a);
        a = fmaf(e3.x, uu3.x, a); a = fmaf(e3.y, uu3.y, a);
        a = fmaf(e3.z, uu3.z, a); a = fmaf(e3.w, uu3.w, a);
        acc[j] = a;
    }
#pragma unroll
    for (int j = 0; j < 8; ++j)
#pragma unroll
        for (int off = 32; off >= 1; off >>= 1)
            acc[j] += __shfl_xor(acc[j], off, 64);

    // --- publish scores at the coherence point (no cache flush) ---
    if (lane == 0) {
        float* sp = scores + (size_t)b * S + s0;
#pragma unroll
        for (int j = 0; j < 8; ++j)
            __hip_atomic_store(sp + j, acc[j], __ATOMIC_RELAXED, __HIP_MEMORY_SCOPE_AGENT);
    }
    // wait for OUR stores only (enc loads are long retired)
    asm volatile("s_waitcnt vmcnt(0)" ::: "memory");

    int old = 0;
    if (lane == 0)
        old = __hip_atomic_fetch_add(&cnt[b], 1, __ATOMIC_RELAXED, __HIP_MEMORY_SCOPE_AGENT);
    old = __shfl(old, 0, 64);

    if (old == 63) {   // last wave for this b: all 512 scores are published
        float v[8];
        const float* rp = scores + (size_t)b * S + lane * 8;
#pragma unroll
        for (int j = 0; j < 8; ++j)
            v[j] = __hip_atomic_load(rp + j, __ATOMIC_RELAXED, __HIP_MEMORY_SCOPE_AGENT);

        float m = v[0];
#pragma unroll
        for (int j = 1; j < 8; ++j) m = fmaxf(m, v[j]);
#pragma unroll
        for (int off = 32; off >= 1; off >>= 1)
            m = fmaxf(m, __shfl_xor(m, off, 64));

        float e[8];
        float sum = 0.f;
#pragma unroll
        for (int j = 0; j < 8; ++j) { e[j] = __expf(v[j] - m); sum += e[j]; }
#pragma unroll
        for (int off = 32; off >= 1; off >>= 1)
            sum += __shfl_xor(sum, off, 64);

        const float inv = 1.f / sum;
        float4* op = reinterpret_cast<float4*>(out + (size_t)b * S + lane * 8);
        op[0] = make_float4(e[0] * inv, e[1] * inv, e[2] * inv, e[3] * inv);
        op[1] = make_float4(e[4] * inv, e[5] * inv, e[6] * inv, e[7] * inv);
    }
}

extern "C" void kernel_launch(void* const* d_in, const int* in_sizes, int n_in,
                              void* d_out, int out_size, void* d_ws, size_t ws_size,
                              hipStream_t stream) {
    const float* hidden = (const float*)d_in[0];   // [1,B,H]
    const float* enc    = (const float*)d_in[1];   // [S,B,H]
    const float* W      = (const float*)d_in[2];   // [H,H]
    // d_in[3] = b_attn: unused — constant per row, cancels in softmax.

    float* u      = (float*)d_ws;                       // B*H floats
    float* scores = u + (size_t)B * H;                  // B*S floats
    float* part   = scores + (size_t)B * S;             // KG*B*H floats
    int*   cnt    = (int*)(part + (size_t)KG * B * H);  // B ints
    float* out    = (float*)d_out;                      // [B,1,S]

    const size_t need_full =
        ((size_t)B * H + (size_t)B * S + (size_t)KG * B * H) * sizeof(float) + B * sizeof(int);
    if (ws_size >= need_full) {
        calc_u_part  <<<KG * BG, 256, 0, stream>>>(hidden, W, part);
        calc_u_reduce<<<(B * H / 4) / 256, 256, 0, stream>>>(part, u, cnt);
    } else {
        cnt = (int*)(scores + (size_t)B * S);
        calc_u_fallback<<<256, 256, 0, stream>>>(hidden, W, u, cnt);
    }
    calc_scores_fused<<<2048, 256, 0, stream>>>(enc, u, scores, cnt, out);
}